// Round 2
// baseline (4609.430 us; speedup 1.0000x reference)
//
#include <hip/hip_runtime.h>
#include <hip/hip_bf16.h>
#include <math.h>

#define T_  64
#define B_  1024
#define E_  300
#define H_  256
#define G3_ 768
#define D_  512
#define CH_ 8   // timesteps per xg chunk (workspace ring)

__device__ __forceinline__ float sigmoidf_(float x){ return 1.0f/(1.0f + expf(-x)); }

// ---------------------------------------------------------------------------
// centroid -> Lorentz map: su[0:512] = unit*sinh(r), su[512] = cosh(r)
// ---------------------------------------------------------------------------
__global__ void lorentz_u_kernel(const float* __restrict__ centroid,
                                 float* __restrict__ su)
{
    __shared__ float red[512];
    const int tid = threadIdx.x;
    float c = centroid[tid];
    red[tid] = c*c;
    __syncthreads();
    for (int s = 256; s > 0; s >>= 1){
        if (tid < s) red[tid] += red[tid + s];
        __syncthreads();
    }
    float rr = sqrtf(red[0]);
    su[tid] = c / rr * sinhf(rr);
    if (tid == 0) su[512] = coshf(rr);
}

// ---------------------------------------------------------------------------
// gathered-A projection GEMM for one chunk of CH_ timesteps:
// xg[r, g] = bih[g] + sum_e emb[tokens[r]][e]*Wih[g][e],  r relative to chunk.
// tokens pointer is pre-offset by caller. rows = CH_*B_, cols = 768.
// Tile 64x64, 256 thr, 4x4 micro.
// ---------------------------------------------------------------------------
__global__ __launch_bounds__(256) void proj_kernel(
    const int* __restrict__ tokens, const float* __restrict__ emb,
    const float* __restrict__ Wih, const float* __restrict__ bih,
    float* __restrict__ xg)
{
    __shared__ float As[64][68];   // [k][row], padded for 16B-aligned float4
    __shared__ float Ws[64][68];   // [k][col]
    const int tid = threadIdx.x;
    const int n0 = blockIdx.x * 64;
    const int m0 = blockIdx.y * 64;
    const int tx = tid & 15, ty = tid >> 4;

    float acc[4][4] = {};

    for (int kc = 0; kc < 5; ++kc){
        const int k0 = kc * 64;
        #pragma unroll
        for (int i = 0; i < 16; ++i){
            int idx = tid + i*256;
            int r = idx >> 6, k = idx & 63;
            int kg = k0 + k;
            float av = 0.f, wv = 0.f;
            if (kg < E_){
                long long tok = tokens[m0 + r];
                av = emb[tok*E_ + kg];
                wv = Wih[(long long)(n0 + r)*E_ + kg];
            }
            As[k][r] = av;
            Ws[k][r] = wv;
        }
        __syncthreads();
        #pragma unroll
        for (int k = 0; k < 64; ++k){
            const float4 a4 = *(const float4*)&As[k][ty*4];
            const float4 w4 = *(const float4*)&Ws[k][tx*4];
            const float a_[4] = {a4.x, a4.y, a4.z, a4.w};
            const float w_[4] = {w4.x, w4.y, w4.z, w4.w};
            #pragma unroll
            for (int i = 0; i < 4; ++i)
                #pragma unroll
                for (int j = 0; j < 4; ++j)
                    acc[i][j] += a_[i] * w_[j];
        }
        __syncthreads();
    }

    const float4 b4 = *(const float4*)&bih[n0 + tx*4];
    const float b_[4] = {b4.x, b4.y, b4.z, b4.w};
    #pragma unroll
    for (int i = 0; i < 4; ++i){
        int row = m0 + ty*4 + i;
        float4 o;
        o.x = acc[i][0] + b_[0];
        o.y = acc[i][1] + b_[1];
        o.z = acc[i][2] + b_[2];
        o.w = acc[i][3] + b_[3];
        *(float4*)&xg[(long long)row*G3_ + n0 + tx*4] = o;
    }
}

// ---------------------------------------------------------------------------
// one GRU time step (one direction): hg = h@Whh^T + bhh, gates, h_new -> f_out
// xg is the chunk buffer holding timesteps [tlo, tlo+CH_).
// grid (8 jblk, 32 bblk), 256 thr. Tile: 32 batch rows x 32 j x 3 gates.
// ---------------------------------------------------------------------------
__global__ __launch_bounds__(256) void gru_step_kernel(
    const float* __restrict__ xg, int tlo, float* __restrict__ f_out,
    const float* __restrict__ hidden, const float* __restrict__ Whh,
    const float* __restrict__ bhh, int dir, int s)
{
    __shared__ float Hs[64][36];   // [k][row], pad 36 for float4 alignment
    __shared__ float Ws[64][97];   // [k][g] g = grp*32+jj
    const int tid = threadIdx.x;
    const int n0 = blockIdx.x * 32;
    const int b0 = blockIdx.y * 32;
    const int tx = tid & 31, ty = tid >> 5;
    const int t = dir ? (63 - s) : s;

    const float* hp; int hstride;
    if (s == 0){ hp = hidden + (long long)dir*B_*H_; hstride = H_; }
    else {
        int tp = dir ? (t + 1) : (t - 1);
        hp = f_out + (long long)tp*B_*D_ + dir*H_;
        hstride = D_;
    }

    float acc[4][3] = {};

    for (int kc = 0; kc < 4; ++kc){
        const int k0 = kc * 64;
        #pragma unroll
        for (int i = 0; i < 8; ++i){
            int idx = tid + i*256;
            int r = idx >> 6, k = idx & 63;
            Hs[k][r] = hp[(long long)(b0 + r)*hstride + k0 + k];
        }
        #pragma unroll
        for (int i = 0; i < 24; ++i){
            int idx = tid + i*256;
            int g = idx >> 6, k = idx & 63;
            int grp = g >> 5, jj = g & 31;
            Ws[k][g] = Whh[(long long)(grp*H_ + n0 + jj)*H_ + k0 + k];
        }
        __syncthreads();
        #pragma unroll
        for (int k = 0; k < 64; ++k){
            const float4 h4 = *(const float4*)&Hs[k][ty*4];
            const float h_[4] = {h4.x, h4.y, h4.z, h4.w};
            const float w0 = Ws[k][tx], w1 = Ws[k][32+tx], w2 = Ws[k][64+tx];
            #pragma unroll
            for (int i = 0; i < 4; ++i){
                acc[i][0] += h_[i]*w0;
                acc[i][1] += h_[i]*w1;
                acc[i][2] += h_[i]*w2;
            }
        }
        __syncthreads();
    }

    const int j = n0 + tx;
    const float bh0 = bhh[j], bh1 = bhh[H_ + j], bh2 = bhh[2*H_ + j];
    #pragma unroll
    for (int i = 0; i < 4; ++i){
        int b = b0 + ty*4 + i;
        const float* xgp = xg + ((long long)(t - tlo)*B_ + b)*G3_;
        float xr = xgp[j], xz = xgp[H_ + j], xn = xgp[2*H_ + j];
        float hr = acc[i][0] + bh0, hz = acc[i][1] + bh1, hn = acc[i][2] + bh2;
        float r_ = sigmoidf_(xr + hr);
        float z_ = sigmoidf_(xz + hz);
        float n_ = tanhf(xn + r_*hn);
        float hprev = hp[(long long)b*hstride + j];
        f_out[((long long)t*B_ + b)*D_ + dir*H_ + j] = (1.f - z_)*n_ + z_*hprev;
    }
}

// ---------------------------------------------------------------------------
// attention GEMM with fused tanh + Lorentz score epilogue.
// Block: 32 rows, loops all 512 cols in 4 chunks of 128. score[r] = -beta*dist
// ---------------------------------------------------------------------------
__global__ __launch_bounds__(256) void attn_score_kernel(
    const float* __restrict__ f_out, const float* __restrict__ attn_W,
    const float* __restrict__ attn_b, const float* __restrict__ su,
    const float* __restrict__ beta, float* __restrict__ score)
{
    __shared__ float Fs[64][36];
    __shared__ float Ws[64][132];
    const int tid = threadIdx.x;
    const int m0 = blockIdx.x * 32;
    const int tx = tid & 31, ty = tid >> 5;

    float pdot[4] = {}, pa2[4] = {};

    for (int nc = 0; nc < 4; ++nc){
        float acc[4][4] = {};
        for (int kc = 0; kc < 8; ++kc){
            const int k0 = kc * 64;
            #pragma unroll
            for (int i = 0; i < 8; ++i){
                int idx = tid + i*256;
                int r = idx >> 6, k = idx & 63;
                Fs[k][r] = f_out[(long long)(m0 + r)*D_ + k0 + k];
            }
            #pragma unroll
            for (int i = 0; i < 32; ++i){
                int idx = tid + i*256;
                int g = idx >> 6, k = idx & 63;
                Ws[k][g] = attn_W[(long long)(nc*128 + g)*D_ + k0 + k];
            }
            __syncthreads();
            #pragma unroll
            for (int k = 0; k < 64; ++k){
                const float4 f4 = *(const float4*)&Fs[k][ty*4];
                const float4 w4 = *(const float4*)&Ws[k][tx*4];
                const float f_[4] = {f4.x, f4.y, f4.z, f4.w};
                const float w_[4] = {w4.x, w4.y, w4.z, w4.w};
                #pragma unroll
                for (int i = 0; i < 4; ++i)
                    #pragma unroll
                    for (int jj = 0; jj < 4; ++jj)
                        acc[i][jj] += f_[i] * w_[jj];
            }
            __syncthreads();
        }
        #pragma unroll
        for (int jj = 0; jj < 4; ++jj){
            int col = nc*128 + tx*4 + jj;
            float bc = attn_b[col], sc = su[col];
            #pragma unroll
            for (int i = 0; i < 4; ++i){
                float av = tanhf(acc[i][jj] + bc);
                pdot[i] += av*sc;
                pa2[i]  += av*av;
            }
        }
    }

    #pragma unroll
    for (int m = 1; m < 32; m <<= 1){
        #pragma unroll
        for (int i = 0; i < 4; ++i){
            pdot[i] += __shfl_xor(pdot[i], m);
            pa2[i]  += __shfl_xor(pa2[i],  m);
        }
    }
    if (tx == 0){
        const float cu = su[512], bb = beta[0];
        #pragma unroll
        for (int i = 0; i < 4; ++i){
            int row = m0 + ty*4 + i;
            float ra  = sqrtf(pa2[i]);
            float shc = sinhf(ra)/ra;
            float prod = cu*coshf(ra) - shc*pdot[i];
            prod = fminf(fmaxf(prod, 1.0f + 1e-7f), 1e16f);
            float dist = logf(prod) + log1pf(sqrtf(prod*prod - 1.0f + 1e-7f)/prod);
            score[row] = -bb * dist;
        }
    }
}

// ---------------------------------------------------------------------------
// per-batch softmax over T, gamma weighting, weighted fK sum; also h_output.
// ---------------------------------------------------------------------------
__global__ __launch_bounds__(256) void pool_kernel(
    const float* __restrict__ f_out, const float* __restrict__ score,
    float* __restrict__ out, float* __restrict__ hout)
{
    __shared__ float rr2s[64];
    __shared__ float wss[64];
    const int tid = threadIdx.x;
    const int b = blockIdx.x;
    const int lane = tid & 63, wv = tid >> 6;

    // phase 1: ||f||^2 per t (each wave handles 16 t's)
    for (int tt = 0; tt < 16; ++tt){
        int t = wv*16 + tt;
        const float* fp = f_out + ((long long)t*B_ + b)*D_ + lane*8;
        float4 a = *(const float4*)fp;
        float4 c = *(const float4*)(fp + 4);
        float s = a.x*a.x + a.y*a.y + a.z*a.z + a.w*a.w
                + c.x*c.x + c.y*c.y + c.z*c.z + c.w*c.w;
        #pragma unroll
        for (int m = 1; m < 64; m <<= 1) s += __shfl_xor(s, m);
        if (lane == 0) rr2s[t] = s;
    }
    __syncthreads();

    // phase 2: softmax * gamma weights (one lane per t, wave 0)
    if (tid < 64){
        int t = tid;
        float sc = score[t*B_ + b];
        float mx = sc;
        #pragma unroll
        for (int m = 1; m < 64; m <<= 1) mx = fmaxf(mx, __shfl_xor(mx, m));
        float e = expf(sc - mx);
        float rr = sqrtf(rr2s[t]);
        float th = tanhf(rr);
        float omt = 1.0f - th*th;
        omt = fminf(fmaxf(omt, 1e-7f), 1.0f - 1e-7f);
        float gamma = 1.0f / sqrtf(omt);
        gamma = fminf(fmaxf(gamma, 1.0f + 1e-7f), 1e16f);
        float w = e * gamma;
        float ssum = w;
        #pragma unroll
        for (int m = 1; m < 64; m <<= 1) ssum += __shfl_xor(ssum, m);
        wss[t] = (w / ssum) * (th / rr);
    }
    __syncthreads();

    // phase 3: out[b][d] = sum_t wss[t] * f[t][b][d]
    #pragma unroll
    for (int dd = 0; dd < 2; ++dd){
        int d = tid + dd*256;
        float acc = 0.f;
        for (int t = 0; t < 64; ++t)
            acc += wss[t] * f_out[((long long)t*B_ + b)*D_ + d];
        out[(long long)b*D_ + d] = acc;
    }

    // phase 4: h_output — h_f = f_out[T-1][b][0:256], h_b = f_out[0][b][256:512]
    {
        int jcol = tid;
        hout[(long long)b*H_ + jcol] = f_out[((long long)(T_-1)*B_ + b)*D_ + jcol];
        hout[(long long)B_*H_ + (long long)b*H_ + jcol] =
            f_out[((long long)0*B_ + b)*D_ + H_ + jcol];
    }
}

// ---------------------------------------------------------------------------
extern "C" void kernel_launch(void* const* d_in, const int* in_sizes, int n_in,
                              void* d_out, int out_size, void* d_ws, size_t ws_size,
                              hipStream_t stream)
{
    const int*   tokens = (const int*)  d_in[0];
    const float* hidden = (const float*)d_in[1];
    const float* emb    = (const float*)d_in[2];
    const float* Wih_f  = (const float*)d_in[3];
    const float* Whh_f  = (const float*)d_in[4];
    const float* bih_f  = (const float*)d_in[5];
    const float* bhh_f  = (const float*)d_in[6];
    const float* Wih_b  = (const float*)d_in[7];
    const float* Whh_b  = (const float*)d_in[8];
    const float* bih_b  = (const float*)d_in[9];
    const float* bhh_b  = (const float*)d_in[10];
    const float* attn_W = (const float*)d_in[11];
    const float* attn_b = (const float*)d_in[12];
    const float* centroid = (const float*)d_in[13];
    const float* beta   = (const float*)d_in[14];

    float* ws    = (float*)d_ws;
    float* f_out = ws;                                   // T*B*512      (134 MB)
    float* xg    = f_out + (long long)T_*B_*D_;          // CH_*B*768    (25 MB)
    float* score = xg + (long long)CH_*B_*G3_;           // T*B          (0.26 MB)
    float* su    = score + (long long)T_*B_;             // 513

    float* out  = (float*)d_out;                         // B*512
    float* hout = out + (long long)B_*D_;                // 2*B*256

    lorentz_u_kernel<<<1, 512, 0, stream>>>(centroid, su);

    // forward direction: chunks of CH_ timesteps
    for (int c = 0; c < T_/CH_; ++c){
        int tlo = c*CH_;
        proj_kernel<<<dim3(12, CH_*16), 256, 0, stream>>>(
            tokens + (long long)tlo*B_, emb, Wih_f, bih_f, xg);
        for (int s = tlo; s < tlo + CH_; ++s)
            gru_step_kernel<<<dim3(8, 32), 256, 0, stream>>>(
                xg, tlo, f_out, hidden, Whh_f, bhh_f, 0, s);
    }

    // backward direction: steps s in [c*CH_, c*CH_+CH_) consume t in [63-s0-CH_+1, 63-s0]
    for (int c = 0; c < T_/CH_; ++c){
        int s0 = c*CH_;
        int tlo = 63 - s0 - (CH_ - 1);
        proj_kernel<<<dim3(12, CH_*16), 256, 0, stream>>>(
            tokens + (long long)tlo*B_, emb, Wih_b, bih_b, xg);
        for (int s = s0; s < s0 + CH_; ++s)
            gru_step_kernel<<<dim3(8, 32), 256, 0, stream>>>(
                xg, tlo, f_out, hidden, Whh_b, bhh_b, 1, s);
    }

    attn_score_kernel<<<2048, 256, 0, stream>>>(f_out, attn_W, attn_b, su, beta, score);
    pool_kernel<<<1024, 256, 0, stream>>>(f_out, score, out, hout);
}

// Round 3
// 2355.075 us; speedup vs baseline: 1.9572x; 1.9572x over previous
//
#include <hip/hip_runtime.h>
#include <hip/hip_bf16.h>
#include <math.h>

#define T_  64
#define B_  1024
#define E_  300
#define EP_ 320     // E padded to multiple of 32
#define H_  256
#define G3_ 768
#define D_  512
#define CH_ 8       // timesteps per xg chunk

typedef float f32x4 __attribute__((ext_vector_type(4)));
typedef short bf16x8 __attribute__((ext_vector_type(8)));

__device__ __forceinline__ float sigmoidf_(float x){ return 1.0f/(1.0f + expf(-x)); }

// ---------------------------------------------------------------------------
// centroid -> Lorentz map: su[0:512] = unit*sinh(r), su[512] = cosh(r)
// ---------------------------------------------------------------------------
__global__ void lorentz_u_kernel(const float* __restrict__ centroid,
                                 float* __restrict__ su)
{
    __shared__ float red[512];
    const int tid = threadIdx.x;
    float c = centroid[tid];
    red[tid] = c*c;
    __syncthreads();
    for (int s = 256; s > 0; s >>= 1){
        if (tid < s) red[tid] += red[tid + s];
        __syncthreads();
    }
    float rr = sqrtf(red[0]);
    su[tid] = c / rr * sinhf(rr);
    if (tid == 0) su[512] = coshf(rr);
}

// ---------------------------------------------------------------------------
// fp32 [rows][ncols] -> bf16 [rows][ncols_pad] with zero pad. block=ncols_pad.
// ---------------------------------------------------------------------------
__global__ void cast_pad_kernel(const float* __restrict__ src,
                                __hip_bfloat16* __restrict__ dst,
                                int ncols, int ncols_pad)
{
    long long r = blockIdx.x;
    int c = threadIdx.x;
    float v = (c < ncols) ? src[r*ncols + c] : 0.f;
    dst[r*ncols_pad + c] = __float2bfloat16(v);
}

// ---------------------------------------------------------------------------
// MFMA projection GEMM (per chunk): xg[r, g] = bih[g] + emb_bf[tok[r]] . Wbf[g]
// grid (12 = 768/64, 128 = 8192/64), 256 thr (4 waves). K = 320 (padded).
// A tile (gathered emb rows) in XOR-swizzled LDS; B frags straight from L2.
// ---------------------------------------------------------------------------
__global__ __launch_bounds__(256) void proj_kernel(
    const int* __restrict__ tokens, const __hip_bfloat16* __restrict__ embbf,
    const __hip_bfloat16* __restrict__ Wbf, const float* __restrict__ bih,
    float* __restrict__ xg)
{
    __shared__ char As[64 * EP_ * 2];   // 40 KB, 64 rows x 40 16B-slots, swizzled
    const int tid = threadIdx.x;
    const int n0 = blockIdx.x * 64;
    const int m0 = blockIdx.y * 64;

    // stage gathered rows: 4 threads per row, 10 slots each
    {
        int row = tid >> 2, sub = tid & 3;
        long long tok = tokens[m0 + row];
        const char* src = (const char*)(embbf + tok * EP_);
        char* dst = As + row * (EP_ * 2);
        int xm = (row & 7);
        #pragma unroll
        for (int j = 0; j < 10; ++j){
            int slot = sub + j*4;
            float4 v = *(const float4*)(src + slot*16);
            *(float4*)(dst + ((slot ^ xm) * 16)) = v;
        }
    }
    __syncthreads();

    const int lane = tid & 63, w = tid >> 6;
    const int arow = w*16 + (lane & 15);
    const int g = lane >> 4;                 // k-group 0..3 (8 k's each)
    const char* abase = As + arow * (EP_ * 2);
    const int amask = arow & 7;

    f32x4 acc[4];
    #pragma unroll
    for (int i = 0; i < 4; ++i) acc[i] = (f32x4){0.f,0.f,0.f,0.f};

    #pragma unroll
    for (int kc = 0; kc < 10; ++kc){
        int aslot = kc*4 + g;
        bf16x8 a = *(const bf16x8*)(abase + ((aslot ^ amask) * 16));
        #pragma unroll
        for (int ct = 0; ct < 4; ++ct){
            int col = n0 + ct*16 + (lane & 15);
            bf16x8 b = *(const bf16x8*)(Wbf + (long long)col*EP_ + kc*32 + g*8);
            acc[ct] = __builtin_amdgcn_mfma_f32_16x16x32_bf16(a, b, acc[ct], 0, 0, 0);
        }
    }

    #pragma unroll
    for (int ct = 0; ct < 4; ++ct){
        int col = n0 + ct*16 + (lane & 15);
        float bv = bih[col];
        int rbase = m0 + w*16 + g*4;
        #pragma unroll
        for (int i = 0; i < 4; ++i)
            xg[(long long)(rbase + i)*G3_ + col] = acc[ct][i] + bv;
    }
}

// ---------------------------------------------------------------------------
// one fused GRU time step, both directions (blockIdx.z = dir). fp32 recurrence
// through hbuf ping-pong; bf16 snapshot to f_bf; final h -> hout (fp32).
// grid (8 jblk, 32 bblk, 2 dir), 256 thr.
// ---------------------------------------------------------------------------
__global__ __launch_bounds__(256) void gru_step_kernel(
    const float* __restrict__ xg_f, const float* __restrict__ xg_b,
    int tlo_f, int tlo_b,
    __hip_bfloat16* __restrict__ f_bf, float* __restrict__ hbuf,
    const float* __restrict__ hidden,
    const float* __restrict__ Whh_f, const float* __restrict__ Whh_b,
    const float* __restrict__ bhh_f, const float* __restrict__ bhh_b,
    float* __restrict__ hout, int s)
{
    const int dir = blockIdx.z;
    const float* Whh = dir ? Whh_b : Whh_f;
    const float* bhh = dir ? bhh_b : bhh_f;
    const float* xg  = dir ? xg_b  : xg_f;
    const int tlo    = dir ? tlo_b : tlo_f;
    const int t      = dir ? (63 - s) : s;

    const float* hp = (s == 0) ? (hidden + (long long)dir*B_*H_)
                               : (hbuf + (long long)(dir*2 + ((s+1)&1))*B_*H_);
    float* hw = hbuf + (long long)(dir*2 + (s&1))*B_*H_;

    __shared__ float Hs[64][36];
    __shared__ float Ws[64][97];
    const int tid = threadIdx.x;
    const int n0 = blockIdx.x * 32;
    const int b0 = blockIdx.y * 32;
    const int tx = tid & 31, ty = tid >> 5;

    float acc[4][3] = {};

    for (int kc = 0; kc < 4; ++kc){
        const int k0 = kc * 64;
        #pragma unroll
        for (int i = 0; i < 8; ++i){
            int idx = tid + i*256;
            int r = idx >> 6, k = idx & 63;
            Hs[k][r] = hp[(long long)(b0 + r)*H_ + k0 + k];
        }
        #pragma unroll
        for (int i = 0; i < 24; ++i){
            int idx = tid + i*256;
            int gg = idx >> 6, k = idx & 63;
            int grp = gg >> 5, jj = gg & 31;
            Ws[k][gg] = Whh[(long long)(grp*H_ + n0 + jj)*H_ + k0 + k];
        }
        __syncthreads();
        #pragma unroll
        for (int k = 0; k < 64; ++k){
            const float4 h4 = *(const float4*)&Hs[k][ty*4];
            const float h_[4] = {h4.x, h4.y, h4.z, h4.w};
            const float w0 = Ws[k][tx], w1 = Ws[k][32+tx], w2 = Ws[k][64+tx];
            #pragma unroll
            for (int i = 0; i < 4; ++i){
                acc[i][0] += h_[i]*w0;
                acc[i][1] += h_[i]*w1;
                acc[i][2] += h_[i]*w2;
            }
        }
        __syncthreads();
    }

    const int j = n0 + tx;
    const float bh0 = bhh[j], bh1 = bhh[H_ + j], bh2 = bhh[2*H_ + j];
    #pragma unroll
    for (int i = 0; i < 4; ++i){
        int b = b0 + ty*4 + i;
        const float* xgp = xg + ((long long)(t - tlo)*B_ + b)*G3_;
        float xr = xgp[j], xz = xgp[H_ + j], xn = xgp[2*H_ + j];
        float hr = acc[i][0] + bh0, hz = acc[i][1] + bh1, hn = acc[i][2] + bh2;
        float r_ = sigmoidf_(xr + hr);
        float z_ = sigmoidf_(xz + hz);
        float n_ = tanhf(xn + r_*hn);
        float hprev = hp[(long long)b*H_ + j];
        float hnew = (1.f - z_)*n_ + z_*hprev;
        hw[(long long)b*H_ + j] = hnew;
        f_bf[((long long)t*B_ + b)*D_ + dir*H_ + j] = __float2bfloat16(hnew);
        if (s == 63) hout[(long long)dir*B_*H_ + (long long)b*H_ + j] = hnew;
    }
}

// ---------------------------------------------------------------------------
// MFMA attention GEMM + fused tanh/Lorentz score. grid 1024 (64 rows each),
// 256 thr. A (f rows) in XOR-swizzled LDS (64 KB); B (attn_W bf16) from L2.
// ---------------------------------------------------------------------------
__global__ __launch_bounds__(256) void attn_score_kernel(
    const __hip_bfloat16* __restrict__ f_bf, const __hip_bfloat16* __restrict__ Wbf,
    const float* __restrict__ attn_b, const float* __restrict__ su,
    const float* __restrict__ beta, float* __restrict__ score)
{
    __shared__ char As[64 * D_ * 2];    // 64 KB: 64 rows x 64 16B-slots, swizzled
    const int tid = threadIdx.x;
    const long long m0 = (long long)blockIdx.x * 64;

    {
        int row = tid >> 2, sub = tid & 3;
        const char* src = (const char*)(f_bf + (m0 + row) * D_);
        char* dst = As + row * (D_ * 2);
        int xm = (row & 7);
        #pragma unroll
        for (int j = 0; j < 16; ++j){
            int slot = sub + j*4;
            float4 v = *(const float4*)(src + slot*16);
            *(float4*)(dst + ((slot ^ xm) * 16)) = v;
        }
    }
    __syncthreads();

    const int lane = tid & 63, w = tid >> 6;
    const int arow = w*16 + (lane & 15);
    const int g = lane >> 4;
    const char* abase = As + arow * (D_ * 2);
    const int amask = arow & 7;

    float pdot[4] = {0,0,0,0}, pa2[4] = {0,0,0,0};

    for (int nc = 0; nc < 8; ++nc){
        f32x4 acc[4];
        #pragma unroll
        for (int i = 0; i < 4; ++i) acc[i] = (f32x4){0.f,0.f,0.f,0.f};
        #pragma unroll
        for (int kc = 0; kc < 16; ++kc){
            int aslot = kc*4 + g;
            bf16x8 a = *(const bf16x8*)(abase + ((aslot ^ amask) * 16));
            #pragma unroll
            for (int ct = 0; ct < 4; ++ct){
                int col = nc*64 + ct*16 + (lane & 15);
                bf16x8 b = *(const bf16x8*)(Wbf + (long long)col*D_ + kc*32 + g*8);
                acc[ct] = __builtin_amdgcn_mfma_f32_16x16x32_bf16(a, b, acc[ct], 0, 0, 0);
            }
        }
        #pragma unroll
        for (int ct = 0; ct < 4; ++ct){
            int col = nc*64 + ct*16 + (lane & 15);
            float bc = attn_b[col], sc = su[col];
            #pragma unroll
            for (int i = 0; i < 4; ++i){
                float av = tanhf(acc[ct][i] + bc);
                pdot[i] += av*sc;
                pa2[i]  += av*av;
            }
        }
    }

    #pragma unroll
    for (int m = 1; m < 16; m <<= 1){
        #pragma unroll
        for (int i = 0; i < 4; ++i){
            pdot[i] += __shfl_xor(pdot[i], m);
            pa2[i]  += __shfl_xor(pa2[i],  m);
        }
    }
    if ((lane & 15) == 0){
        const float cu = su[512], bb = beta[0];
        #pragma unroll
        for (int i = 0; i < 4; ++i){
            long long row = m0 + w*16 + g*4 + i;
            float ra  = sqrtf(pa2[i]);
            float shc = sinhf(ra)/ra;
            float prod = cu*coshf(ra) - shc*pdot[i];
            prod = fminf(fmaxf(prod, 1.0f + 1e-7f), 1e16f);
            float dist = logf(prod) + log1pf(sqrtf(prod*prod - 1.0f + 1e-7f)/prod);
            score[row] = -bb * dist;
        }
    }
}

// ---------------------------------------------------------------------------
// per-batch softmax over T, gamma weighting, weighted fK sum (bf16 f input).
// ---------------------------------------------------------------------------
__global__ __launch_bounds__(256) void pool_kernel(
    const __hip_bfloat16* __restrict__ f_bf, const float* __restrict__ score,
    float* __restrict__ out)
{
    __shared__ float rr2s[64];
    __shared__ float wss[64];
    const int tid = threadIdx.x;
    const long long b = blockIdx.x;
    const int lane = tid & 63, wv = tid >> 6;

    for (int tt = 0; tt < 16; ++tt){
        int t = wv*16 + tt;
        const __hip_bfloat16* fp = f_bf + ((long long)t*B_ + b)*D_ + lane*8;
        float4 v = *(const float4*)fp;
        const __hip_bfloat16* hb = (const __hip_bfloat16*)&v;
        float s = 0.f;
        #pragma unroll
        for (int q = 0; q < 8; ++q){ float x = __bfloat162float(hb[q]); s += x*x; }
        #pragma unroll
        for (int m = 1; m < 64; m <<= 1) s += __shfl_xor(s, m);
        if (lane == 0) rr2s[t] = s;
    }
    __syncthreads();

    if (tid < 64){
        int t = tid;
        float sc = score[t*B_ + b];
        float mx = sc;
        #pragma unroll
        for (int m = 1; m < 64; m <<= 1) mx = fmaxf(mx, __shfl_xor(mx, m));
        float e = expf(sc - mx);
        float rr = sqrtf(rr2s[t]);
        float th = tanhf(rr);
        float omt = 1.0f - th*th;
        omt = fminf(fmaxf(omt, 1e-7f), 1.0f - 1e-7f);
        float gamma = 1.0f / sqrtf(omt);
        gamma = fminf(fmaxf(gamma, 1.0f + 1e-7f), 1e16f);
        float wgt = e * gamma;
        float ssum = wgt;
        #pragma unroll
        for (int m = 1; m < 64; m <<= 1) ssum += __shfl_xor(ssum, m);
        wss[t] = (wgt / ssum) * (th / rr);
    }
    __syncthreads();

    #pragma unroll
    for (int dd = 0; dd < 2; ++dd){
        int d = tid + dd*256;
        float acc = 0.f;
        for (int t = 0; t < 64; ++t)
            acc += wss[t] * __bfloat162float(f_bf[((long long)t*B_ + b)*D_ + d]);
        out[b*D_ + d] = acc;
    }
}

// ---------------------------------------------------------------------------
extern "C" void kernel_launch(void* const* d_in, const int* in_sizes, int n_in,
                              void* d_out, int out_size, void* d_ws, size_t ws_size,
                              hipStream_t stream)
{
    const int*   tokens = (const int*)  d_in[0];
    const float* hidden = (const float*)d_in[1];
    const float* emb    = (const float*)d_in[2];
    const float* Wih_f  = (const float*)d_in[3];
    const float* Whh_f  = (const float*)d_in[4];
    const float* bih_f  = (const float*)d_in[5];
    const float* bhh_f  = (const float*)d_in[6];
    const float* Wih_b  = (const float*)d_in[7];
    const float* Whh_b  = (const float*)d_in[8];
    const float* bih_b  = (const float*)d_in[9];
    const float* bhh_b  = (const float*)d_in[10];
    const float* attn_W = (const float*)d_in[11];
    const float* attn_b = (const float*)d_in[12];
    const float* centroid = (const float*)d_in[13];
    const float* beta   = (const float*)d_in[14];

    const int V = in_sizes[2] / E_;

    char* w = (char*)d_ws;
    __hip_bfloat16* f_bf  = (__hip_bfloat16*)w;  w += (size_t)T_*B_*D_*2;      // 64 MiB
    float*          xg_f  = (float*)w;           w += (size_t)CH_*B_*G3_*4;    // 24 MiB
    float*          xg_b  = (float*)w;           w += (size_t)CH_*B_*G3_*4;    // 24 MiB
    float*          hbuf  = (float*)w;           w += (size_t)4*B_*H_*4;       // 4 MiB
    __hip_bfloat16* embbf = (__hip_bfloat16*)w;  w += (size_t)V*EP_*2;         // 30.5 MiB
    __hip_bfloat16* wihf  = (__hip_bfloat16*)w;  w += (size_t)G3_*EP_*2;
    __hip_bfloat16* wihb  = (__hip_bfloat16*)w;  w += (size_t)G3_*EP_*2;
    __hip_bfloat16* wat   = (__hip_bfloat16*)w;  w += (size_t)D_*D_*2;
    float*          score = (float*)w;           w += (size_t)T_*B_*4;
    float*          su    = (float*)w;           w += 513*4;

    float* out  = (float*)d_out;                 // B*512
    float* hout = out + (long long)B_*D_;        // 2*B*256

    lorentz_u_kernel<<<1, 512, 0, stream>>>(centroid, su);
    cast_pad_kernel<<<V,   EP_, 0, stream>>>(emb,    embbf, E_, EP_);
    cast_pad_kernel<<<G3_, EP_, 0, stream>>>(Wih_f,  wihf,  E_, EP_);
    cast_pad_kernel<<<G3_, EP_, 0, stream>>>(Wih_b,  wihb,  E_, EP_);
    cast_pad_kernel<<<D_,  D_,  0, stream>>>(attn_W, wat,   D_, D_);

    for (int c = 0; c < T_/CH_; ++c){
        const int tlo_f = c*CH_;
        const int tlo_b = (T_ - CH_) - c*CH_;
        proj_kernel<<<dim3(12, 128), 256, 0, stream>>>(
            tokens + (long long)tlo_f*B_, embbf, wihf, bih_f, xg_f);
        proj_kernel<<<dim3(12, 128), 256, 0, stream>>>(
            tokens + (long long)tlo_b*B_, embbf, wihb, bih_b, xg_b);
        for (int s = tlo_f; s < tlo_f + CH_; ++s)
            gru_step_kernel<<<dim3(8, 32, 2), 256, 0, stream>>>(
                xg_f, xg_b, tlo_f, tlo_b, f_bf, hbuf, hidden,
                Whh_f, Whh_b, bhh_f, bhh_b, hout, s);
    }

    attn_score_kernel<<<1024, 256, 0, stream>>>(f_bf, wat, attn_b, su, beta, score);
    pool_kernel<<<1024, 256, 0, stream>>>(f_bf, score, out);
}

// Round 4
// 1645.516 us; speedup vs baseline: 2.8012x; 1.4312x over previous
//
#include <hip/hip_runtime.h>
#include <hip/hip_bf16.h>
#include <math.h>

#define T_  64
#define B_  1024
#define E_  300
#define EP_ 320     // E padded to multiple of 32
#define H_  256
#define G3_ 768
#define D_  512
#define CH_ 8       // timesteps per xg chunk

typedef float f32x4 __attribute__((ext_vector_type(4)));
typedef short bf16x8 __attribute__((ext_vector_type(8)));

__device__ __forceinline__ float sigmoidf_(float x){ return 1.0f/(1.0f + expf(-x)); }

__device__ __forceinline__ bf16x8 pack8(const float* p){
    union { bf16x8 v; __hip_bfloat16 h[8]; } u;
    #pragma unroll
    for (int q = 0; q < 8; ++q) u.h[q] = __float2bfloat16(p[q]);
    return u.v;
}

// ---------------------------------------------------------------------------
// centroid -> Lorentz map: su[0:512] = unit*sinh(r), su[512] = cosh(r)
// ---------------------------------------------------------------------------
__global__ void lorentz_u_kernel(const float* __restrict__ centroid,
                                 float* __restrict__ su)
{
    __shared__ float red[512];
    const int tid = threadIdx.x;
    float c = centroid[tid];
    red[tid] = c*c;
    __syncthreads();
    for (int s = 256; s > 0; s >>= 1){
        if (tid < s) red[tid] += red[tid + s];
        __syncthreads();
    }
    float rr = sqrtf(red[0]);
    su[tid] = c / rr * sinhf(rr);
    if (tid == 0) su[512] = coshf(rr);
}

// ---------------------------------------------------------------------------
// fp32 [rows][ncols] -> bf16 [rows][ncols_pad] with zero pad. block=ncols_pad.
// ---------------------------------------------------------------------------
__global__ void cast_pad_kernel(const float* __restrict__ src,
                                __hip_bfloat16* __restrict__ dst,
                                int ncols, int ncols_pad)
{
    long long r = blockIdx.x;
    int c = threadIdx.x;
    float v = (c < ncols) ? src[r*ncols + c] : 0.f;
    dst[r*ncols_pad + c] = __float2bfloat16(v);
}

// ---------------------------------------------------------------------------
// MFMA projection GEMM (per chunk): xg[r, g] = bih[g] + emb_bf[tok[r]] . Wbf[g]
// grid (12, 128), 256 thr. K = 320 (padded). A tile in XOR-swizzled LDS.
// ---------------------------------------------------------------------------
__global__ __launch_bounds__(256) void proj_kernel(
    const int* __restrict__ tokens, const __hip_bfloat16* __restrict__ embbf,
    const __hip_bfloat16* __restrict__ Wbf, const float* __restrict__ bih,
    float* __restrict__ xg)
{
    __shared__ char As[64 * EP_ * 2];   // 40 KB
    const int tid = threadIdx.x;
    const int n0 = blockIdx.x * 64;
    const int m0 = blockIdx.y * 64;

    {
        int row = tid >> 2, sub = tid & 3;
        long long tok = tokens[m0 + row];
        const char* src = (const char*)(embbf + tok * EP_);
        char* dst = As + row * (EP_ * 2);
        int xm = (row & 7);
        #pragma unroll
        for (int j = 0; j < 10; ++j){
            int slot = sub + j*4;
            float4 v = *(const float4*)(src + slot*16);
            *(float4*)(dst + ((slot ^ xm) * 16)) = v;
        }
    }
    __syncthreads();

    const int lane = tid & 63, w = tid >> 6;
    const int arow = w*16 + (lane & 15);
    const int g = lane >> 4;
    const char* abase = As + arow * (EP_ * 2);
    const int amask = arow & 7;

    f32x4 acc[4];
    #pragma unroll
    for (int i = 0; i < 4; ++i) acc[i] = (f32x4){0.f,0.f,0.f,0.f};

    #pragma unroll
    for (int kc = 0; kc < 10; ++kc){
        int aslot = kc*4 + g;
        bf16x8 a = *(const bf16x8*)(abase + ((aslot ^ amask) * 16));
        #pragma unroll
        for (int ct = 0; ct < 4; ++ct){
            int col = n0 + ct*16 + (lane & 15);
            bf16x8 b = *(const bf16x8*)(Wbf + (long long)col*EP_ + kc*32 + g*8);
            acc[ct] = __builtin_amdgcn_mfma_f32_16x16x32_bf16(a, b, acc[ct], 0, 0, 0);
        }
    }

    #pragma unroll
    for (int ct = 0; ct < 4; ++ct){
        int col = n0 + ct*16 + (lane & 15);
        float bv = bih[col];
        int rbase = m0 + w*16 + g*4;
        #pragma unroll
        for (int i = 0; i < 4; ++i)
            xg[(long long)(rbase + i)*G3_ + col] = acc[ct][i] + bv;
    }
}

// ---------------------------------------------------------------------------
// MFMA GRU step, both dirs. grid (16 jblk, 16 bblk, 2 dir), 256 thr, no LDS.
// A = h (bf16 ping-pong), B = Whh_bf (L2-resident). fp32 carry in hf32.
// Block: 64 b-rows x 16 j x 3 gates. Wave w: rows b0+w*16.. ; 3x8 MFMAs.
// ---------------------------------------------------------------------------
__global__ __launch_bounds__(256) void gru_step_kernel(
    const float* __restrict__ xg_f, const float* __restrict__ xg_b,
    int tlo_f, int tlo_b,
    __hip_bfloat16* __restrict__ f_bf,
    __hip_bfloat16* __restrict__ hbf,      // [2 parity][2 dir][B][H]
    float* __restrict__ hf32,              // [2 dir][B][H]
    const float* __restrict__ hidden,
    const __hip_bfloat16* __restrict__ whhbf,  // [2 dir][768][256]
    const float* __restrict__ bhh_f, const float* __restrict__ bhh_b,
    float* __restrict__ hout, int s)
{
    const int dir = blockIdx.z;
    const int j0 = blockIdx.x * 16;
    const int b0 = blockIdx.y * 64;
    const int tid = threadIdx.x;
    const int lane = tid & 63, w = tid >> 6;
    const int g = lane >> 4, l15 = lane & 15;
    const int t = dir ? (63 - s) : s;
    const float* xg  = dir ? xg_b  : xg_f;
    const int tlo    = dir ? tlo_b : tlo_f;
    const float* bhh = dir ? bhh_b : bhh_f;
    const __hip_bfloat16* Wb = whhbf + (size_t)dir*G3_*H_;

    // A-fragments for this wave's 16 rows
    bf16x8 a[8];
    const int arow = b0 + w*16 + l15;
    if (s == 0){
        const float* hp = hidden + ((size_t)dir*B_ + arow)*H_;
        #pragma unroll
        for (int kc = 0; kc < 8; ++kc)
            a[kc] = pack8(hp + kc*32 + g*8);
    } else {
        const __hip_bfloat16* hp = hbf + (((size_t)(s&1)*2 + dir)*B_ + arow)*H_;
        #pragma unroll
        for (int kc = 0; kc < 8; ++kc)
            a[kc] = *(const bf16x8*)(hp + kc*32 + g*8);
    }

    f32x4 acc[3];
    #pragma unroll
    for (int i = 0; i < 3; ++i) acc[i] = (f32x4){0.f,0.f,0.f,0.f};

    #pragma unroll
    for (int kc = 0; kc < 8; ++kc){
        #pragma unroll
        for (int grp = 0; grp < 3; ++grp){
            bf16x8 b = *(const bf16x8*)(Wb + ((size_t)(grp*H_ + j0 + l15))*H_ + kc*32 + g*8);
            acc[grp] = __builtin_amdgcn_mfma_f32_16x16x32_bf16(a[kc], b, acc[grp], 0, 0, 0);
        }
    }

    const int j = j0 + l15;
    const float bh0 = bhh[j], bh1 = bhh[H_ + j], bh2 = bhh[2*H_ + j];
    float* hfp = hf32 + (size_t)dir*B_*H_;
    __hip_bfloat16* hw = hbf + ((size_t)(((s+1)&1)*2 + dir))*B_*H_;
    #pragma unroll
    for (int i = 0; i < 4; ++i){
        int b = b0 + w*16 + g*4 + i;
        const float* xgp = xg + ((size_t)(t - tlo)*B_ + b)*G3_;
        float xr = xgp[j], xz = xgp[H_ + j], xn = xgp[2*H_ + j];
        float hprev = (s == 0) ? hidden[((size_t)dir*B_ + b)*H_ + j]
                               : hfp[(size_t)b*H_ + j];
        float hr = acc[0][i] + bh0, hz = acc[1][i] + bh1, hn = acc[2][i] + bh2;
        float r_ = sigmoidf_(xr + hr);
        float z_ = sigmoidf_(xz + hz);
        float n_ = tanhf(xn + r_*hn);
        float hnew = (1.f - z_)*n_ + z_*hprev;
        hfp[(size_t)b*H_ + j] = hnew;
        hw[(size_t)b*H_ + j] = __float2bfloat16(hnew);
        f_bf[((size_t)t*B_ + b)*D_ + dir*H_ + j] = __float2bfloat16(hnew);
        if (s == 63) hout[(size_t)dir*B_*H_ + (size_t)b*H_ + j] = hnew;
    }
}

// ---------------------------------------------------------------------------
// MFMA attention GEMM + fused tanh/Lorentz score. 1024 blocks x 256 thr.
// A-fragments in registers (no LDS, no barriers); B streamed from L2.
// ---------------------------------------------------------------------------
__global__ __launch_bounds__(256, 4) void attn_score_kernel(
    const __hip_bfloat16* __restrict__ f_bf, const __hip_bfloat16* __restrict__ Wbf,
    const float* __restrict__ attn_b, const float* __restrict__ su,
    const float* __restrict__ beta, float* __restrict__ score)
{
    const int tid = threadIdx.x;
    const int lane = tid & 63, w = tid >> 6;
    const int g = lane >> 4, l15 = lane & 15;
    const long long m0 = (long long)blockIdx.x * 64;
    const long long arow = m0 + w*16 + l15;

    bf16x8 a[16];
    const __hip_bfloat16* ap = f_bf + arow*D_;
    #pragma unroll
    for (int kc = 0; kc < 16; ++kc)
        a[kc] = *(const bf16x8*)(ap + kc*32 + g*8);

    float pdot[4] = {0,0,0,0}, pa2[4] = {0,0,0,0};

    for (int nc = 0; nc < 8; ++nc){
        f32x4 acc[4];
        #pragma unroll
        for (int i = 0; i < 4; ++i) acc[i] = (f32x4){0.f,0.f,0.f,0.f};
        #pragma unroll
        for (int kc = 0; kc < 16; ++kc){
            #pragma unroll
            for (int ct = 0; ct < 4; ++ct){
                int col = nc*64 + ct*16 + l15;
                bf16x8 b = *(const bf16x8*)(Wbf + (long long)col*D_ + kc*32 + g*8);
                acc[ct] = __builtin_amdgcn_mfma_f32_16x16x32_bf16(a[kc], b, acc[ct], 0, 0, 0);
            }
        }
        #pragma unroll
        for (int ct = 0; ct < 4; ++ct){
            int col = nc*64 + ct*16 + l15;
            float bc = attn_b[col], sc = su[col];
            #pragma unroll
            for (int i = 0; i < 4; ++i){
                float av = tanhf(acc[ct][i] + bc);
                pdot[i] += av*sc;
                pa2[i]  += av*av;
            }
        }
    }

    #pragma unroll
    for (int m = 1; m < 16; m <<= 1){
        #pragma unroll
        for (int i = 0; i < 4; ++i){
            pdot[i] += __shfl_xor(pdot[i], m);
            pa2[i]  += __shfl_xor(pa2[i],  m);
        }
    }
    if (l15 == 0){
        const float cu = su[512], bb = beta[0];
        #pragma unroll
        for (int i = 0; i < 4; ++i){
            long long row = m0 + w*16 + g*4 + i;
            float ra  = sqrtf(pa2[i]);
            float shc = sinhf(ra)/ra;
            float prod = cu*coshf(ra) - shc*pdot[i];
            prod = fminf(fmaxf(prod, 1.0f + 1e-7f), 1e16f);
            float dist = logf(prod) + log1pf(sqrtf(prod*prod - 1.0f + 1e-7f)/prod);
            score[row] = -bb * dist;
        }
    }
}

// ---------------------------------------------------------------------------
// per-batch softmax over T, gamma weighting, weighted fK sum (bf16 f input).
// ---------------------------------------------------------------------------
__global__ __launch_bounds__(256) void pool_kernel(
    const __hip_bfloat16* __restrict__ f_bf, const float* __restrict__ score,
    float* __restrict__ out)
{
    __shared__ float rr2s[64];
    __shared__ float wss[64];
    const int tid = threadIdx.x;
    const long long b = blockIdx.x;
    const int lane = tid & 63, wv = tid >> 6;

    for (int tt = 0; tt < 16; ++tt){
        int t = wv*16 + tt;
        const __hip_bfloat16* fp = f_bf + ((long long)t*B_ + b)*D_ + lane*8;
        float4 v = *(const float4*)fp;
        const __hip_bfloat16* hb = (const __hip_bfloat16*)&v;
        float s = 0.f;
        #pragma unroll
        for (int q = 0; q < 8; ++q){ float x = __bfloat162float(hb[q]); s += x*x; }
        #pragma unroll
        for (int m = 1; m < 64; m <<= 1) s += __shfl_xor(s, m);
        if (lane == 0) rr2s[t] = s;
    }
    __syncthreads();

    if (tid < 64){
        int t = tid;
        float sc = score[t*B_ + b];
        float mx = sc;
        #pragma unroll
        for (int m = 1; m < 64; m <<= 1) mx = fmaxf(mx, __shfl_xor(mx, m));
        float e = expf(sc - mx);
        float rr = sqrtf(rr2s[t]);
        float th = tanhf(rr);
        float omt = 1.0f - th*th;
        omt = fminf(fmaxf(omt, 1e-7f), 1.0f - 1e-7f);
        float gamma = 1.0f / sqrtf(omt);
        gamma = fminf(fmaxf(gamma, 1.0f + 1e-7f), 1e16f);
        float wgt = e * gamma;
        float ssum = wgt;
        #pragma unroll
        for (int m = 1; m < 64; m <<= 1) ssum += __shfl_xor(ssum, m);
        wss[t] = (wgt / ssum) * (th / rr);
    }
    __syncthreads();

    #pragma unroll
    for (int dd = 0; dd < 2; ++dd){
        int d = tid + dd*256;
        float acc = 0.f;
        for (int t = 0; t < 64; ++t)
            acc += wss[t] * __bfloat162float(f_bf[((long long)t*B_ + b)*D_ + d]);
        out[b*D_ + d] = acc;
    }
}

// ---------------------------------------------------------------------------
extern "C" void kernel_launch(void* const* d_in, const int* in_sizes, int n_in,
                              void* d_out, int out_size, void* d_ws, size_t ws_size,
                              hipStream_t stream)
{
    const int*   tokens = (const int*)  d_in[0];
    const float* hidden = (const float*)d_in[1];
    const float* emb    = (const float*)d_in[2];
    const float* Wih_f  = (const float*)d_in[3];
    const float* Whh_f  = (const float*)d_in[4];
    const float* bih_f  = (const float*)d_in[5];
    const float* bhh_f  = (const float*)d_in[6];
    const float* Wih_b  = (const float*)d_in[7];
    const float* Whh_b  = (const float*)d_in[8];
    const float* bih_b  = (const float*)d_in[9];
    const float* bhh_b  = (const float*)d_in[10];
    const float* attn_W = (const float*)d_in[11];
    const float* attn_b = (const float*)d_in[12];
    const float* centroid = (const float*)d_in[13];
    const float* beta   = (const float*)d_in[14];

    const int V = in_sizes[2] / E_;

    char* w = (char*)d_ws;
    __hip_bfloat16* f_bf  = (__hip_bfloat16*)w;  w += (size_t)T_*B_*D_*2;      // 64 MiB
    float*          xg_f  = (float*)w;           w += (size_t)CH_*B_*G3_*4;    // 24 MiB
    float*          xg_b  = (float*)w;           w += (size_t)CH_*B_*G3_*4;    // 24 MiB
    __hip_bfloat16* hbf   = (__hip_bfloat16*)w;  w += (size_t)4*B_*H_*2;       // 2 MiB (2 parity x 2 dir)
    float*          hf32  = (float*)w;           w += (size_t)2*B_*H_*4;       // 2 MiB
    __hip_bfloat16* embbf = (__hip_bfloat16*)w;  w += (size_t)V*EP_*2;         // 30.5 MiB
    __hip_bfloat16* wihf  = (__hip_bfloat16*)w;  w += (size_t)G3_*EP_*2;
    __hip_bfloat16* wihb  = (__hip_bfloat16*)w;  w += (size_t)G3_*EP_*2;
    __hip_bfloat16* whhbf = (__hip_bfloat16*)w;  w += (size_t)2*G3_*H_*2;      // 0.75 MiB
    __hip_bfloat16* wat   = (__hip_bfloat16*)w;  w += (size_t)D_*D_*2;
    float*          score = (float*)w;           w += (size_t)T_*B_*4;
    float*          su    = (float*)w;           w += 513*4;

    float* out  = (float*)d_out;                 // B*512
    float* hout = out + (long long)B_*D_;        // 2*B*256

    lorentz_u_kernel<<<1, 512, 0, stream>>>(centroid, su);
    cast_pad_kernel<<<V,   EP_, 0, stream>>>(emb,    embbf, E_, EP_);
    cast_pad_kernel<<<G3_, EP_, 0, stream>>>(Wih_f,  wihf,  E_, EP_);
    cast_pad_kernel<<<G3_, EP_, 0, stream>>>(Wih_b,  wihb,  E_, EP_);
    cast_pad_kernel<<<G3_, H_,  0, stream>>>(Whh_f,  whhbf,            H_, H_);
    cast_pad_kernel<<<G3_, H_,  0, stream>>>(Whh_b,  whhbf + (size_t)G3_*H_, H_, H_);
    cast_pad_kernel<<<D_,  D_,  0, stream>>>(attn_W, wat,   D_, D_);

    for (int c = 0; c < T_/CH_; ++c){
        const int tlo_f = c*CH_;
        const int tlo_b = (T_ - CH_) - c*CH_;
        proj_kernel<<<dim3(12, 128), 256, 0, stream>>>(
            tokens + (long long)tlo_f*B_, embbf, wihf, bih_f, xg_f);
        proj_kernel<<<dim3(12, 128), 256, 0, stream>>>(
            tokens + (long long)tlo_b*B_, embbf, wihb, bih_b, xg_b);
        for (int s = tlo_f; s < tlo_f + CH_; ++s)
            gru_step_kernel<<<dim3(16, 16, 2), 256, 0, stream>>>(
                xg_f, xg_b, tlo_f, tlo_b, f_bf, hbf, hf32, hidden,
                whhbf, bhh_f, bhh_b, hout, s);
    }

    attn_score_kernel<<<1024, 256, 0, stream>>>(f_bf, wat, attn_b, su, beta, score);
    pool_kernel<<<1024, 256, 0, stream>>>(f_bf, score, out);
}